// Round 9
// baseline (1555.233 us; speedup 1.0000x reference)
//
#include <hip/hip_runtime.h>

// Graphormer-style multi-head attention.
// B=16, N=512, HID=1024, H=16, D=64, T_HOP=32, T_EDGE=64, SCALE=1/8.
//
// R6 resubmit #3 (GPUAcquisitionTimeout / container failures; no data yet).
//  - pack_he pre-pass: hop|edge<<8 -> u16 [B][N][N]; attn stages a 64x64
//    index tile into LDS via global_load_lds (coalesced) instead of 32
//    scattered global dwords/thread/tile (which serialized under VGPR
//    pressure = the 812us mystery).
//  - softmax streams in place in S[4] (no hv/ev/val/p arrays): ~80 VGPR.
//  - epilogue loads unrolled 4x.
//  gemm_mfma / type_scores / split_bf16 byte-identical to R5.

#define SCALE 0.125f

typedef __attribute__((ext_vector_type(8))) short bf16x8;
typedef __attribute__((ext_vector_type(4))) float f32x4;

__device__ __forceinline__ ushort f2bf(float x) {
    unsigned u = __float_as_uint(x);
    return (ushort)((u + 0x7FFF + ((u >> 16) & 1)) >> 16);
}
__device__ __forceinline__ float bf2f(ushort h) {
    return __uint_as_float(((unsigned)h) << 16);
}

__device__ __forceinline__ void stage16(const ushort* g, ushort* l) {
    __builtin_amdgcn_global_load_lds(
        (const __attribute__((address_space(1))) unsigned int*)g,
        (__attribute__((address_space(3))) unsigned int*)l, 16, 0, 0);
}

// ---------------------------------------------------------------------------
// pack hop/edge int32 -> u16 (hop | edge<<8)
// ---------------------------------------------------------------------------
__global__ __launch_bounds__(256) void pack_he(
    const int* __restrict__ hop, const int* __restrict__ edge,
    ushort* __restrict__ he, int n)
{
    const int stride = gridDim.x * 256 * 4;
    for (int i = (blockIdx.x * 256 + threadIdx.x) * 4; i < n; i += stride) {
        int4 hv = *(const int4*)&hop[i];
        int4 ev = *(const int4*)&edge[i];
        ushort4 o;
        o.x = (ushort)(hv.x | (ev.x << 8));
        o.y = (ushort)(hv.y | (ev.y << 8));
        o.z = (ushort)(hv.z | (ev.z << 8));
        o.w = (ushort)(hv.w | (ev.w << 8));
        *(ushort4*)&he[i] = o;
    }
}

// ---------------------------------------------------------------------------
// split fp32 -> bf16 hi + lo residual  (unchanged)
// ---------------------------------------------------------------------------
__global__ __launch_bounds__(256) void split_bf16(
    const float* __restrict__ in, ushort* __restrict__ oh,
    ushort* __restrict__ ol, int n)
{
    const int stride = gridDim.x * 256 * 4;
    for (int i = (blockIdx.x * 256 + threadIdx.x) * 4; i < n; i += stride) {
        float4 v = *(const float4*)&in[i];
        ushort4 h, l;
        h.x = f2bf(v.x); l.x = f2bf(v.x - bf2f(h.x));
        h.y = f2bf(v.y); l.y = f2bf(v.y - bf2f(h.y));
        h.z = f2bf(v.z); l.z = f2bf(v.z - bf2f(h.z));
        h.w = f2bf(v.w); l.w = f2bf(v.w - bf2f(h.w));
        *(ushort4*)&oh[i] = h;
        *(ushort4*)&ol[i] = l;
    }
}

// ---------------------------------------------------------------------------
// MFMA GEMM (unchanged from R5)
// ---------------------------------------------------------------------------
__global__ __launch_bounds__(256) void gemm_mfma(
    const ushort* __restrict__ Ah, const ushort* __restrict__ Al,
    const ushort* __restrict__ Bh, const ushort* __restrict__ Bl,
    const float* __restrict__ bias, float* __restrict__ Cf,
    ushort* __restrict__ Ch, ushort* __restrict__ Cl, int layout)
{
    __shared__ ushort sAh[4096];
    __shared__ ushort sAl[4096];
    __shared__ ushort sBh[2048];
    __shared__ ushort sBl[2048];

    const int tid = threadIdx.x;
    const int m0 = blockIdx.x * 128, n0 = blockIdx.y * 64;
    const int l = tid & 63, w = tid >> 6;
    const int wr = w >> 1, wc = w & 1;
    const int koff = l >> 4, r16 = l & 15;

    f32x4 acc[4][2] = {};

    const int sa0 = tid, sa1 = tid + 256;
    const int ar0 = sa0 & 127, ak0 = sa0 >> 7;
    const int ar1 = sa1 & 127, ak1 = sa1 >> 7;
    const int bn = tid & 63, bk = tid >> 6;

    const ushort* gAh0 = Ah + (size_t)(m0 + ar0) * 1024 + ak0 * 8;
    const ushort* gAh1 = Ah + (size_t)(m0 + ar1) * 1024 + ak1 * 8;
    const ushort* gAl0 = Al + (size_t)(m0 + ar0) * 1024 + ak0 * 8;
    const ushort* gAl1 = Al + (size_t)(m0 + ar1) * 1024 + ak1 * 8;
    const ushort* gBh0 = Bh + (size_t)(n0 + bn) * 1024 + bk * 8;
    const ushort* gBl0 = Bl + (size_t)(n0 + bn) * 1024 + bk * 8;

    for (int kt = 0; kt < 32; ++kt) {
        const int k0 = kt * 32;
        __syncthreads();
        stage16(gAh0 + k0, &sAh[sa0 * 8]);
        stage16(gAh1 + k0, &sAh[sa1 * 8]);
        stage16(gAl0 + k0, &sAl[sa0 * 8]);
        stage16(gAl1 + k0, &sAl[sa1 * 8]);
        stage16(gBh0 + k0, &sBh[tid * 8]);
        stage16(gBl0 + k0, &sBl[tid * 8]);
        __syncthreads();

        bf16x8 fah[4], fal[4], fbh[2], fbl[2];
#pragma unroll
        for (int mi = 0; mi < 4; ++mi) {
            const int off = (koff * 128 + wr * 64 + mi * 16 + r16) * 8;
            fah[mi] = *(const bf16x8*)&sAh[off];
            fal[mi] = *(const bf16x8*)&sAl[off];
        }
#pragma unroll
        for (int ni = 0; ni < 2; ++ni) {
            const int off = (koff * 64 + wc * 32 + ni * 16 + r16) * 8;
            fbh[ni] = *(const bf16x8*)&sBh[off];
            fbl[ni] = *(const bf16x8*)&sBl[off];
        }
#pragma unroll
        for (int mi = 0; mi < 4; ++mi)
#pragma unroll
            for (int ni = 0; ni < 2; ++ni) {
                acc[mi][ni] = __builtin_amdgcn_mfma_f32_16x16x32_bf16(
                    fah[mi], fbh[ni], acc[mi][ni], 0, 0, 0);
                acc[mi][ni] = __builtin_amdgcn_mfma_f32_16x16x32_bf16(
                    fah[mi], fbl[ni], acc[mi][ni], 0, 0, 0);
                acc[mi][ni] = __builtin_amdgcn_mfma_f32_16x16x32_bf16(
                    fal[mi], fbh[ni], acc[mi][ni], 0, 0, 0);
            }
    }

#pragma unroll
    for (int mi = 0; mi < 4; ++mi) {
        const int rowb = m0 + wr * 64 + mi * 16 + (l >> 4) * 4;
#pragma unroll
        for (int ni = 0; ni < 2; ++ni) {
            const int col = n0 + wc * 32 + ni * 16 + (l & 15);
            const float bb = bias[col];
            float v[4];
#pragma unroll
            for (int r = 0; r < 4; ++r) v[r] = acc[mi][ni][r] + bb;
            if (layout == 0) {
#pragma unroll
                for (int r = 0; r < 4; ++r)
                    Cf[(size_t)(rowb + r) * 1024 + col] = v[r];
            } else if (layout == 1) {
                const int b16_ = rowb >> 9, i2 = rowb & 511;
                const int hh = col >> 6, dd = col & 63;
                const size_t base = ((size_t)(b16_ * 16 + hh) * 512 + i2) * 64 + dd;
#pragma unroll
                for (int r = 0; r < 4; ++r) {
                    ushort hv_ = f2bf(v[r]);
                    Ch[base + (size_t)r * 64] = hv_;
                    Cl[base + (size_t)r * 64] = f2bf(v[r] - bf2f(hv_));
                }
            } else {
                const int b16_ = rowb >> 9, i2 = rowb & 511;
                const int hh = col >> 6, dd = col & 63;
                ushort4 pk;
                pk.x = f2bf(v[0]); pk.y = f2bf(v[1]);
                pk.z = f2bf(v[2]); pk.w = f2bf(v[3]);
                *(ushort4*)&Ch[((size_t)(b16_ * 16 + hh) * 64 + dd) * 512 + i2] = pk;
            }
        }
    }
}

// ---------------------------------------------------------------------------
// Type scores (unchanged from R5)
// ---------------------------------------------------------------------------
__global__ __launch_bounds__(256) void type_scores(
    const ushort* __restrict__ Qh, const ushort* __restrict__ Ql,
    const ushort* __restrict__ Kh, const ushort* __restrict__ Kl,
    const float* __restrict__ qhe, const float* __restrict__ qee,
    const float* __restrict__ khe, const float* __restrict__ kee,
    ushort* __restrict__ Shop, ushort* __restrict__ Sedge)
{
    __shared__ float qs[64][65];
    __shared__ float ks[64][65];
    const int tid = threadIdx.x;
    const int i0 = (blockIdx.x & 7) * 64;
    const int bh = blockIdx.x >> 3;
    const int h = bh & 15;
    {
        const int r = tid >> 2, c16 = (tid & 3) << 4;
        const size_t off = ((size_t)bh * 512 + i0 + r) * 64 + c16;
        ushort tqh[16], tql[16], tkh[16], tkl[16];
        *(uint4*)&tqh[0] = *(const uint4*)&Qh[off];
        *(uint4*)&tqh[8] = *(const uint4*)&Qh[off + 8];
        *(uint4*)&tql[0] = *(const uint4*)&Ql[off];
        *(uint4*)&tql[8] = *(const uint4*)&Ql[off + 8];
        *(uint4*)&tkh[0] = *(const uint4*)&Kh[off];
        *(uint4*)&tkh[8] = *(const uint4*)&Kh[off + 8];
        *(uint4*)&tkl[0] = *(const uint4*)&Kl[off];
        *(uint4*)&tkl[8] = *(const uint4*)&Kl[off + 8];
#pragma unroll
        for (int u = 0; u < 16; ++u) {
            qs[r][c16 + u] = bf2f(tqh[u]) + bf2f(tql[u]);
            ks[r][c16 + u] = bf2f(tkh[u]) + bf2f(tkl[u]);
        }
    }
    __syncthreads();
    const int i = tid & 63;
    const int tq = tid >> 6;
    for (int tt = 0; tt < 24; ++tt) {
        int t96 = tq * 24 + tt;
        const float *eq, *ek;
        ushort* outp;
        if (t96 < 32) {
            eq = qhe + t96 * 1024 + h * 64;
            ek = khe + t96 * 1024 + h * 64;
            outp = &Shop[((size_t)bh * 512 + i0 + i) * 32 + t96];
        } else {
            int t = t96 - 32;
            eq = qee + t * 1024 + h * 64;
            ek = kee + t * 1024 + h * 64;
            outp = &Sedge[((size_t)bh * 512 + i0 + i) * 64 + t];
        }
        float s0 = 0.f, s1 = 0.f, s2 = 0.f, s3 = 0.f;
#pragma unroll 4
        for (int d = 0; d < 64; d += 4) {
            s0 += qs[i][d + 0] * eq[d + 0] + ks[i][d + 0] * ek[d + 0];
            s1 += qs[i][d + 1] * eq[d + 1] + ks[i][d + 1] * ek[d + 1];
            s2 += qs[i][d + 2] * eq[d + 2] + ks[i][d + 2] * ek[d + 2];
            s3 += qs[i][d + 3] * eq[d + 3] + ks[i][d + 3] * ek[d + 3];
        }
        *outp = f2bf((s0 + s1) + (s2 + s3));
    }
}

// ---------------------------------------------------------------------------
// MFMA fused attention. Block = (b,h, 64 q-rows), 256 thr = 4 waves x 16 rows.
// Indices staged to LDS; softmax in place in S; ~80 VGPR.
// ---------------------------------------------------------------------------
__global__ __launch_bounds__(256) void attn_mfma(
    const ushort* __restrict__ Qh, const ushort* __restrict__ Ql,
    const ushort* __restrict__ Kh, const ushort* __restrict__ Kl,
    const ushort* __restrict__ Vtb,
    const ushort* __restrict__ ShopB, const ushort* __restrict__ SedgeB,
    const ushort* __restrict__ heP,
    const float* __restrict__ vhe, const float* __restrict__ vee,
    float* __restrict__ Y)
{
    __shared__ ushort sKh[4096];     // 64 j x 64 d bf16, XOR-swizzled rows
    __shared__ ushort sKl[4096];
    __shared__ ushort sVt[4096];     // 64 d x 64 j bf16, swizzled
    __shared__ ushort sP[4096];      // 4 waves x 16 x 64 bf16, swizzled
    __shared__ ushort sHE[4096];     // 64 i x 64 j packed hop|edge<<8
    __shared__ ushort sShop[2048];   // 64 x 32 bf16
    __shared__ ushort sSedge[4096];  // 64 x 64 bf16
    __shared__ float vha[2112];      // 64 x 33
    __shared__ float vea[4160];      // 64 x 65

    const int tid = threadIdx.x;
    const int bid = blockIdx.x;
    const int swz = (bid & 7) * 256 + (bid >> 3);   // XCD-contiguous bh
    const int it = swz & 7, h = (swz >> 3) & 15, b = swz >> 7;
    const int bh = b * 16 + h;
    const int i0 = it * 64;

    const int l = tid & 63, w = tid >> 6;
    const int l15 = l & 15, lhi = l >> 4;
    const int xorv = (l15 & 7) << 4;

    // prologue: bias tables -> LDS, zero bins
    {
        const ushort* sh = ShopB + ((size_t)bh * 512 + i0) * 32 + tid * 8;
        *(uint4*)&sShop[tid * 8] = *(const uint4*)sh;
        const ushort* se = SedgeB + ((size_t)bh * 512 + i0) * 64 + tid * 16;
        *(uint4*)&sSedge[tid * 16] = *(const uint4*)se;
        *(uint4*)&sSedge[tid * 16 + 8] = *(const uint4*)(se + 8);
    }
    for (int i = tid; i < 2112; i += 256) vha[i] = 0.f;
    for (int i = tid; i < 4160; i += 256) vea[i] = 0.f;

    // Q fragments (rows i0 + w*16 + l15)
    bf16x8 qfh[2], qfl[2];
    {
        const size_t q0 = ((size_t)bh * 512 + i0 + w * 16 + l15) * 64 + lhi * 8;
        qfh[0] = *(const bf16x8*)&Qh[q0];
        qfh[1] = *(const bf16x8*)&Qh[q0 + 32];
        qfl[0] = *(const bf16x8*)&Ql[q0];
        qfl[1] = *(const bf16x8*)&Ql[q0 + 32];
    }

    f32x4 accO[4] = {};
    float m_run[4] = {-1e30f, -1e30f, -1e30f, -1e30f};
    float l_run[4] = {0.f, 0.f, 0.f, 0.f};

    const int sj = tid >> 3;
    const int sc = ((tid & 7) ^ (sj & 7)) * 8;   // inverse-swizzled src column
    const size_t kb = (size_t)bh * 32768;
    // he staging: wave w covers local rows w*16..w*16+15 (its own rows)
    const ushort* heb = heP + ((size_t)b * 512 + i0 + w * 16 + (l >> 3)) * 512 + (l & 7) * 8;

    const char* sKhB = (const char*)sKh;
    const char* sKlB = (const char*)sKl;
    const char* sVtB = (const char*)sVt;
    char* sPB = (char*)sP;
    const int wpb = w * 2048;

    for (int t = 0; t < 8; ++t) {
        const int j0 = t * 64;
        __syncthreads();   // (A) done reading prev tile LDS
        stage16(&Kh[kb + (size_t)(j0 + sj) * 64 + sc], &sKh[tid * 8]);
        stage16(&Kh[kb + (size_t)(j0 + sj + 32) * 64 + sc], &sKh[(tid + 256) * 8]);
        stage16(&Kl[kb + (size_t)(j0 + sj) * 64 + sc], &sKl[tid * 8]);
        stage16(&Kl[kb + (size_t)(j0 + sj + 32) * 64 + sc], &sKl[(tid + 256) * 8]);
        stage16(&Vtb[kb + (size_t)sj * 512 + j0 + sc], &sVt[tid * 8]);
        stage16(&Vtb[kb + (size_t)(sj + 32) * 512 + j0 + sc], &sVt[(tid + 256) * 8]);
        stage16(heb + j0, &sHE[w * 1024 + l * 8]);
        stage16(heb + j0 + 8 * 512, &sHE[w * 1024 + 512 + l * 8]);
        __syncthreads();   // (B) staged + vmcnt drained

        // ---- QK^T (split-bf16: hh + hl + lh) ----
        f32x4 S[4] = {};
#pragma unroll
        for (int ks = 0; ks < 2; ++ks) {
            const int rb2 = (ks * 64 + lhi * 16) ^ xorv;
#pragma unroll
            for (int cf = 0; cf < 4; ++cf) {
                const int jrow = (cf * 16 + l15) * 128;
                bf16x8 kh_ = *(const bf16x8*)(sKhB + jrow + rb2);
                bf16x8 kl_ = *(const bf16x8*)(sKlB + jrow + rb2);
                S[cf] = __builtin_amdgcn_mfma_f32_16x16x32_bf16(qfh[ks], kh_, S[cf], 0, 0, 0);
                S[cf] = __builtin_amdgcn_mfma_f32_16x16x32_bf16(qfh[ks], kl_, S[cf], 0, 0, 0);
                S[cf] = __builtin_amdgcn_mfma_f32_16x16x32_bf16(qfl[ks], kh_, S[cf], 0, 0, 0);
            }
        }

        // ---- bias add in place (indices from LDS) ----
#pragma unroll
        for (int cf = 0; cf < 4; ++cf)
#pragma unroll
            for (int r = 0; r < 4; ++r) {
                const int rg = w * 16 + lhi * 4 + r;
                const unsigned he = sHE[rg * 64 + cf * 16 + l15];
                S[cf][r] = (S[cf][r] + bf2f(sShop[rg * 32 + (he & 255u)])
                            + bf2f(sSedge[rg * 64 + (he >> 8)])) * SCALE;
            }

        // ---- online max (16-lane groups), defer-max THR=10 ----
        float tmax[4];
#pragma unroll
        for (int r = 0; r < 4; ++r) {
            float tm = fmaxf(fmaxf(S[0][r], S[1][r]), fmaxf(S[2][r], S[3][r]));
            tm = fmaxf(tm, __shfl_xor(tm, 1));
            tm = fmaxf(tm, __shfl_xor(tm, 2));
            tm = fmaxf(tm, __shfl_xor(tm, 4));
            tm = fmaxf(tm, __shfl_xor(tm, 8));
            tmax[r] = tm;
        }
        const bool need = (tmax[0] > m_run[0] + 10.f) || (tmax[1] > m_run[1] + 10.f) ||
                          (tmax[2] > m_run[2] + 10.f) || (tmax[3] > m_run[3] + 10.f);
        if (__any(need)) {   // rare after tile 0
#pragma unroll
            for (int r = 0; r < 4; ++r) {
                const float mn = fmaxf(m_run[r], tmax[r]);
                const float al = __expf(m_run[r] - mn);
                m_run[r] = mn;
                l_run[r] *= al;
                accO[0][r] *= al; accO[1][r] *= al;
                accO[2][r] *= al; accO[3][r] *= al;
                const int rg = w * 16 + lhi * 4 + r;
                vha[rg * 33 + l15] *= al;
                vha[rg * 33 + 16 + l15] *= al;
                vea[rg * 65 + l15] *= al;
                vea[rg * 65 + 16 + l15] *= al;
                vea[rg * 65 + 32 + l15] *= al;
                vea[rg * 65 + 48 + l15] *= al;
            }
            asm volatile("" ::: "memory");
        }

        // ---- exp in place + row sums ----
        float ps[4] = {0.f, 0.f, 0.f, 0.f};
#pragma unroll
        for (int cf = 0; cf < 4; ++cf)
#pragma unroll
            for (int r = 0; r < 4; ++r) {
                const float pe = __expf(S[cf][r] - m_run[r]);
                S[cf][r] = pe;
                ps[r] += pe;
            }
#pragma unroll
        for (int r = 0; r < 4; ++r) {
            float s_ = ps[r];
            s_ += __shfl_xor(s_, 1);
            s_ += __shfl_xor(s_, 2);
            s_ += __shfl_xor(s_, 4);
            s_ += __shfl_xor(s_, 8);
            l_run[r] += s_;
        }

        // ---- bins + P -> LDS (bf16, swizzled) ----
#pragma unroll
        for (int cf = 0; cf < 4; ++cf)
#pragma unroll
            for (int r = 0; r < 4; ++r) {
                const int rg = w * 16 + lhi * 4 + r;
                const unsigned he = sHE[rg * 64 + cf * 16 + l15];
                const float pv = S[cf][r];
                atomicAdd(&vha[rg * 33 + (he & 255u)], pv);
                atomicAdd(&vea[rg * 65 + (he >> 8)], pv);
                const int rl = lhi * 4 + r;
                *(ushort*)(sPB + wpb + rl * 128 +
                           ((cf * 32 + l15 * 2) ^ ((rl & 7) << 4))) = f2bf(pv);
            }
        asm volatile("" ::: "memory");   // wave-internal P visibility

        // ---- PV (single bf16) ----
#pragma unroll
        for (int ks = 0; ks < 2; ++ks) {
            const int rb2 = (ks * 64 + lhi * 16) ^ xorv;
            bf16x8 pa = *(const bf16x8*)(sPB + wpb + l15 * 128 + rb2);
#pragma unroll
            for (int cf = 0; cf < 4; ++cf) {
                bf16x8 vb = *(const bf16x8*)(sVtB + (cf * 16 + l15) * 128 + rb2);
                accO[cf] = __builtin_amdgcn_mfma_f32_16x16x32_bf16(pa, vb, accO[cf], 0, 0, 0);
            }
        }
    }
    asm volatile("" ::: "memory");

    // ---- epilogue: normalize, + vha@vhe + vea@vee, store ----
    float inv[4];
#pragma unroll
    for (int r = 0; r < 4; ++r) inv[r] = 1.0f / l_run[r];
    float o[16];
#pragma unroll
    for (int cf = 0; cf < 4; ++cf)
#pragma unroll
        for (int r = 0; r < 4; ++r) o[cf * 4 + r] = accO[cf][r] * inv[r];

    const int rgb = w * 16 + lhi * 4;
#pragma unroll 4
    for (int tt = 0; tt < 32; ++tt) {
        float wn[4];
#pragma unroll
        for (int r = 0; r < 4; ++r) wn[r] = vha[(rgb + r) * 33 + tt] * inv[r];
        const float* g = vhe + (size_t)tt * 1024 + h * 64 + l15;
#pragma unroll
        for (int cf = 0; cf < 4; ++cf) {
            const float gv = g[cf * 16];
#pragma unroll
            for (int r = 0; r < 4; ++r) o[cf * 4 + r] += wn[r] * gv;
        }
    }
#pragma unroll 4
    for (int tt = 0; tt < 64; ++tt) {
        float wn[4];
#pragma unroll
        for (int r = 0; r < 4; ++r) wn[r] = vea[(rgb + r) * 65 + tt] * inv[r];
        const float* g = vee + (size_t)tt * 1024 + h * 64 + l15;
#pragma unroll
        for (int cf = 0; cf < 4; ++cf) {
            const float gv = g[cf * 16];
#pragma unroll
            for (int r = 0; r < 4; ++r) o[cf * 4 + r] += wn[r] * gv;
        }
    }
#pragma unroll
    for (int r = 0; r < 4; ++r) {
        float* yp = Y + ((size_t)b * 512 + i0 + rgb + r) * 1024 + h * 64 + l15;
#pragma unroll
        for (int cf = 0; cf < 4; ++cf) yp[cf * 16] = o[cf * 4 + r];
    }
}

// ---------------------------------------------------------------------------
extern "C" void kernel_launch(void* const* d_in, const int* in_sizes, int n_in,
                              void* d_out, int out_size, void* d_ws, size_t ws_size,
                              hipStream_t stream)
{
    (void)in_sizes; (void)n_in; (void)out_size; (void)ws_size;
    const float* x   = (const float*)d_in[0];
    const float* qhe = (const float*)d_in[1];
    const float* qee = (const float*)d_in[2];
    const float* khe = (const float*)d_in[3];
    const float* kee = (const float*)d_in[4];
    const float* vhe = (const float*)d_in[5];
    const float* vee = (const float*)d_in[6];
    const int*   hop = (const int*)d_in[7];
    const int*   edg = (const int*)d_in[8];
    const float* Wq = (const float*)d_in[9];  const float* bq = (const float*)d_in[10];
    const float* Wk = (const float*)d_in[11]; const float* bk = (const float*)d_in[12];
    const float* Wv = (const float*)d_in[13]; const float* bv = (const float*)d_in[14];
    const float* Wo = (const float*)d_in[15]; const float* bo = (const float*)d_in[16];

    ushort* Qh    = (ushort*)d_ws;
    ushort* Ql    = Qh + 8388608;
    ushort* Kh    = Ql + 8388608;
    ushort* Kl    = Kh + 8388608;
    ushort* VtB   = Kl + 8388608;
    ushort* ShopB = VtB + 8388608;
    ushort* SedgeB= ShopB + 4194304;
    ushort* heB   = SedgeB + 8388608;           // 4194304 u16
    float*  Yb    = (float*)(heB + 4194304);
    ushort* xh    = (ushort*)(Yb + 8388608);
    ushort* xl    = xh + 8388608;
    ushort* wh    = xl + 8388608;
    ushort* wl    = wh + 1048576;

    const dim3 gG(64, 16);

    pack_he<<<2048, 256, 0, stream>>>(hop, edg, heB, 4194304);
    split_bf16<<<2048, 256, 0, stream>>>(x, xh, xl, 8388608);
    split_bf16<<<512, 256, 0, stream>>>(Wq, wh, wl, 1048576);
    gemm_mfma<<<gG, 256, 0, stream>>>(xh, xl, wh, wl, bq, nullptr, Qh, Ql, 1);
    split_bf16<<<512, 256, 0, stream>>>(Wk, wh, wl, 1048576);
    gemm_mfma<<<gG, 256, 0, stream>>>(xh, xl, wh, wl, bk, nullptr, Kh, Kl, 1);
    split_bf16<<<512, 256, 0, stream>>>(Wv, wh, wl, 1048576);
    gemm_mfma<<<gG, 256, 0, stream>>>(xh, xl, wh, wl, bv, nullptr, VtB, nullptr, 2);

    type_scores<<<2048, 256, 0, stream>>>(Qh, Ql, Kh, Kl, qhe, qee, khe, kee,
                                          ShopB, SedgeB);
    attn_mfma<<<2048, 256, 0, stream>>>(Qh, Ql, Kh, Kl, VtB, ShopB, SedgeB,
                                        heB, vhe, vee, Yb);

    split_bf16<<<2048, 256, 0, stream>>>(Yb, xh, xl, 8388608);
    split_bf16<<<512, 256, 0, stream>>>(Wo, wh, wl, 1048576);
    gemm_mfma<<<gG, 256, 0, stream>>>(xh, xl, wh, wl, bo, (float*)d_out,
                                      nullptr, nullptr, 0);
}